// Round 9
// baseline (441.501 us; speedup 1.0000x reference)
//
#include <hip/hip_runtime.h>
#include <hip/hip_bf16.h>
#include <cstddef>

#define BB 4
#define LL 2048
#define DM 256
#define DN 512
#define EE 1024
#define NS 16
#define RK 16
#define NC2 64          // scan chunks
#define CL2 (LL / NC2)  // chunk length = 32

typedef __attribute__((ext_vector_type(8))) short bf16x8;
typedef __attribute__((ext_vector_type(8))) unsigned short ushort8;
typedef __attribute__((ext_vector_type(4))) unsigned short ushort4v;
typedef __attribute__((ext_vector_type(4))) float f32x4;

__device__ __forceinline__ float fsilu(float x) { return x / (1.0f + __expf(-x)); }
__device__ __forceinline__ float fsoftplus(float x) { return x > 20.0f ? x : log1pf(__expf(x)); }
__device__ __forceinline__ unsigned short f2bf(float x) {  // RNE float->bf16
  union { float f; unsigned int u; } v; v.f = x;
  unsigned int r = v.u + 0x7fffu + ((v.u >> 16) & 1u);
  return (unsigned short)(r >> 16);
}

// ---------------------------------------------------------------------------
// in_proj via bf16 MFMA. Block: 128e x 128l, 4 waves (2x2), wave 64x64 =
// 4x4 MFMA 16x16x32. x-blocks (e<DN): C[e][l] -> xz[b][e][l].
// z-blocks: swap A/B so C[l][d] -> z_t[b][l][d] = silu (coalesced).
// ---------------------------------------------------------------------------
__global__ __launch_bounds__(256) void in_proj_mfma(
    const float* __restrict__ h, const float* __restrict__ w,
    float* __restrict__ xz, float* __restrict__ z_t) {
  __shared__ unsigned short ht[128][40];  // [l][k] bf16, 80B row (16B aligned)
  __shared__ unsigned short wt[128][40];  // [e][k]
  const int b = blockIdx.z;
  const int e0 = blockIdx.y * 128;
  const int l0 = blockIdx.x * 128;
  const int tid = threadIdx.x;
  const int lane = tid & 63;
  const int wid = tid >> 6;
  const int wm = wid >> 1, wn = wid & 1;
  const bool zblk = (e0 >= DN);
  const int krow = (lane >> 4) * 8;
  const int rlo = lane & 15;

  f32x4 acc[4][4];
#pragma unroll
  for (int i = 0; i < 4; i++)
#pragma unroll
    for (int j = 0; j < 4; j++) acc[i][j] = (f32x4){0.f, 0.f, 0.f, 0.f};

  for (int dk = 0; dk < DM; dk += 32) {
#pragma unroll
    for (int it = 0; it < 2; it++) {
      int idx = it * 256 + tid;
      int row = idx >> 2;
      int seg = (idx & 3) * 8;
      const float* hp = h + ((size_t)b * LL + l0 + row) * DM + dk + seg;
      float4 ha = *(const float4*)hp, hb = *(const float4*)(hp + 4);
      ushort8 hv;
      hv[0] = f2bf(ha.x); hv[1] = f2bf(ha.y); hv[2] = f2bf(ha.z); hv[3] = f2bf(ha.w);
      hv[4] = f2bf(hb.x); hv[5] = f2bf(hb.y); hv[6] = f2bf(hb.z); hv[7] = f2bf(hb.w);
      *(ushort8*)&ht[row][seg] = hv;
      const float* wp = w + (size_t)(e0 + row) * DM + dk + seg;
      float4 wa = *(const float4*)wp, wb = *(const float4*)(wp + 4);
      ushort8 wv;
      wv[0] = f2bf(wa.x); wv[1] = f2bf(wa.y); wv[2] = f2bf(wa.z); wv[3] = f2bf(wa.w);
      wv[4] = f2bf(wb.x); wv[5] = f2bf(wb.y); wv[6] = f2bf(wb.z); wv[7] = f2bf(wb.w);
      *(ushort8*)&wt[row][seg] = wv;
    }
    __syncthreads();
    unsigned short (*Ab)[40] = zblk ? ht : wt;
    unsigned short (*Bb)[40] = zblk ? wt : ht;
    bf16x8 af[4], bfr[4];
#pragma unroll
    for (int mt = 0; mt < 4; mt++)
      af[mt] = *(bf16x8*)&Ab[wm * 64 + mt * 16 + rlo][krow];
#pragma unroll
    for (int nt = 0; nt < 4; nt++)
      bfr[nt] = *(bf16x8*)&Bb[wn * 64 + nt * 16 + rlo][krow];
#pragma unroll
    for (int mt = 0; mt < 4; mt++)
#pragma unroll
      for (int nt = 0; nt < 4; nt++)
        acc[mt][nt] = __builtin_amdgcn_mfma_f32_16x16x32_bf16(
            af[mt], bfr[nt], acc[mt][nt], 0, 0, 0);
    __syncthreads();
  }
  if (!zblk) {
#pragma unroll
    for (int mt = 0; mt < 4; mt++)
#pragma unroll
      for (int nt = 0; nt < 4; nt++)
#pragma unroll
        for (int r = 0; r < 4; r++) {
          int e = e0 + wm * 64 + mt * 16 + (lane >> 4) * 4 + r;
          int l = l0 + wn * 64 + nt * 16 + rlo;
          xz[((size_t)b * DN + e) * LL + l] = acc[mt][nt][r];
        }
  } else {
#pragma unroll
    for (int mt = 0; mt < 4; mt++)
#pragma unroll
      for (int nt = 0; nt < 4; nt++)
#pragma unroll
        for (int r = 0; r < 4; r++) {
          int l = l0 + wm * 64 + mt * 16 + (lane >> 4) * 4 + r;
          int d = (e0 - DN) + wn * 64 + nt * 16 + rlo;
          z_t[((size_t)b * LL + l) * DN + d] = fsilu(acc[mt][nt][r]);
        }
  }
}

// ---------------------------------------------------------------------------
// conv_kernel: pure streaming conv+silu+transpose. Block = (128 d-chunk, 32 l).
// Grid (LL/32 * 4, BB, 2) = 2048 blocks. Writes u[b][l][d].
// ---------------------------------------------------------------------------
__global__ __launch_bounds__(256) void conv_kernel(
    const float* __restrict__ xz,
    const float* __restrict__ cw_f, const float* __restrict__ cb_f,
    const float* __restrict__ cw_r, const float* __restrict__ cb_r,
    float* __restrict__ u_f, float* __restrict__ u_r) {
  __shared__ float xt[128][33];
  const int rev = blockIdx.z;
  const int b = blockIdx.y;
  const int dc0 = (blockIdx.x & 3) * 128;
  const int l0 = (blockIdx.x >> 2) * 32;
  const int tid = threadIdx.x;
  const int lc = tid & 31;
  const int dg = tid >> 5;  // 0..7
  const int l = l0 + lc;
  const float* conv_w = rev ? cw_r : cw_f;
  const float* conv_b = rev ? cb_r : cb_f;
  float* u_out = rev ? u_r : u_f;

#pragma unroll
  for (int i = 0; i < 16; i++) {
    int dloc = dg * 16 + i;
    int dd = dc0 + dloc;
    const float* base = xz + ((size_t)b * DN + dd) * LL;
    float4 cw4 = *(const float4*)(conv_w + dd * 4);
    float a0 = conv_b[dd];
    if (rev) {
      a0 = fmaf(cw4.w, base[l], a0);
      if (l + 1 < LL) a0 = fmaf(cw4.z, base[l + 1], a0);
      if (l + 2 < LL) a0 = fmaf(cw4.y, base[l + 2], a0);
      if (l + 3 < LL) a0 = fmaf(cw4.x, base[l + 3], a0);
    } else {
      a0 = fmaf(cw4.w, base[l], a0);
      if (l - 1 >= 0) a0 = fmaf(cw4.z, base[l - 1], a0);
      if (l - 2 >= 0) a0 = fmaf(cw4.y, base[l - 2], a0);
      if (l - 3 >= 0) a0 = fmaf(cw4.x, base[l - 3], a0);
    }
    xt[dloc][lc] = fsilu(a0);
  }
  __syncthreads();
#pragma unroll
  for (int j = 0; j < 16; j++) {
    int idx = j * 256 + tid;
    int dd = idx & 127;
    int l2 = idx >> 7;
    u_out[((size_t)b * LL + l0 + l2) * DN + dc0 + dd] = xt[dd][l2];
  }
}

// ---------------------------------------------------------------------------
// xdbl_kernel: x_dbl GEMM (48 x 64l x 512) via MFMA on u[b][t][d], then
// fused delta = softplus(dt_w @ dt + b) with transposed store.
// Block = 64 l, 4 waves; wave = n-tile. Grid (LL/64, BB, 2).
// LDS union: phase1 {ub[64][136]bf, xwb[48][136]bf}, phase2 {dtw_c[128][17],
// dout[128][65]} in one smem buffer; dtv[16][65] separate.
// ---------------------------------------------------------------------------
__global__ __launch_bounds__(256) void xdbl_kernel(
    const float* __restrict__ u_f, const float* __restrict__ u_r,
    const float* __restrict__ xw_f, const float* __restrict__ dtw_f,
    const float* __restrict__ dtb_f,
    const float* __restrict__ xw_r, const float* __restrict__ dtw_r,
    const float* __restrict__ dtb_r,
    float* __restrict__ dl_f, float* __restrict__ B_f, float* __restrict__ C_f,
    float* __restrict__ dl_r, float* __restrict__ B_r, float* __restrict__ C_r) {
  __shared__ float smem[10496];  // 41984 B
  __shared__ float dtv[16][65];
  unsigned short(*ub)[136] = (unsigned short(*)[136])smem;            // 17408 B
  unsigned short(*xwb)[136] = (unsigned short(*)[136])(smem + 4352);  // 13056 B
  float(*dtw_c)[17] = (float(*)[17])smem;                             //  8704 B
  float(*dout)[65] = (float(*)[65])(smem + 2176);                     // 33280 B

  const int rev = blockIdx.z;
  const int b = blockIdx.y;
  const int l0 = blockIdx.x * 64;
  const int tid = threadIdx.x;
  const int lane = tid & 63;
  const int w = tid >> 6;  // wave = n-tile 0..3
  const int rlo = lane & 15;
  const int kseg = (lane >> 4) * 8;

  const float* up = (rev ? u_r : u_f) + ((size_t)b * LL + l0) * DN;
  const float* x_w = rev ? xw_r : xw_f;
  const float* dt_w = rev ? dtw_r : dtw_f;
  const float* dt_b = rev ? dtb_r : dtb_f;
  float* dl_out = rev ? dl_r : dl_f;
  float* B_out = rev ? B_r : B_f;
  float* C_out = rev ? C_r : C_f;

  f32x4 am0 = (f32x4){0.f, 0.f, 0.f, 0.f};
  f32x4 am1 = (f32x4){0.f, 0.f, 0.f, 0.f};
  f32x4 am2 = (f32x4){0.f, 0.f, 0.f, 0.f};

  for (int kc = 0; kc < 4; kc++) {
    // stage u tile [64 l][128 d] -> bf16
#pragma unroll
    for (int j = 0; j < 8; j++) {
      int idx = j * 256 + tid;
      int l2 = idx >> 5;
      int s4 = (idx & 31) * 4;
      float4 v = *(const float4*)(up + (size_t)l2 * DN + kc * 128 + s4);
      ushort4v t4;
      t4[0] = f2bf(v.x); t4[1] = f2bf(v.y); t4[2] = f2bf(v.z); t4[3] = f2bf(v.w);
      *(ushort4v*)&ub[l2][s4] = t4;
    }
    // stage x_w chunk [48][128] -> bf16
#pragma unroll
    for (int j = 0; j < 6; j++) {
      int idx = j * 256 + tid;
      int r = idx >> 5;
      int s4 = (idx & 31) * 4;
      float4 v = *(const float4*)(x_w + (size_t)r * DN + kc * 128 + s4);
      ushort4v t4;
      t4[0] = f2bf(v.x); t4[1] = f2bf(v.y); t4[2] = f2bf(v.z); t4[3] = f2bf(v.w);
      *(ushort4v*)&xwb[r][s4] = t4;
    }
    __syncthreads();
#pragma unroll
    for (int ks = 0; ks < 4; ks++) {
      bf16x8 bfrag = *(bf16x8*)&ub[w * 16 + rlo][ks * 32 + kseg];
      bf16x8 a0 = *(bf16x8*)&xwb[0 * 16 + rlo][ks * 32 + kseg];
      bf16x8 a1 = *(bf16x8*)&xwb[1 * 16 + rlo][ks * 32 + kseg];
      bf16x8 a2 = *(bf16x8*)&xwb[2 * 16 + rlo][ks * 32 + kseg];
      am0 = __builtin_amdgcn_mfma_f32_16x16x32_bf16(a0, bfrag, am0, 0, 0, 0);
      am1 = __builtin_amdgcn_mfma_f32_16x16x32_bf16(a1, bfrag, am1, 0, 0, 0);
      am2 = __builtin_amdgcn_mfma_f32_16x16x32_bf16(a2, bfrag, am2, 0, 0, 0);
    }
    __syncthreads();
  }
  // unload: rows 0-15 -> dtv (LDS), 16-31 -> B, 32-47 -> C
  {
    const int rbase = (lane >> 4) * 4;
    const int lcol = w * 16 + rlo;
#pragma unroll
    for (int r = 0; r < 4; r++) dtv[rbase + r][lcol] = am0[r];
#pragma unroll
    for (int r = 0; r < 4; r++)
      B_out[((size_t)b * LL + l0 + lcol) * NS + rbase + r] = am1[r];
#pragma unroll
    for (int r = 0; r < 4; r++)
      C_out[((size_t)b * LL + l0 + lcol) * NS + rbase + r] = am2[r];
  }
  __syncthreads();

  // delta: 4 chunks of 128 d
  const int dloc = tid & 127;
  const int lh = tid >> 7;  // 0 or 1
  for (int dchunk = 0; dchunk < 4; dchunk++) {
    int d0 = dchunk * 128;
    // stage dt_w chunk [128][16]
#pragma unroll
    for (int j = 0; j < 2; j++) {
      int idx = j * 256 + tid;
      int r = idx >> 2;
      int s4 = (idx & 3) * 4;
      float4 v = *(const float4*)(dt_w + (size_t)(d0 + r) * RK + s4);
      dtw_c[r][s4] = v.x; dtw_c[r][s4 + 1] = v.y;
      dtw_c[r][s4 + 2] = v.z; dtw_c[r][s4 + 3] = v.w;
    }
    __syncthreads();
    float wreg[16];
#pragma unroll
    for (int k = 0; k < 16; k++) wreg[k] = dtw_c[dloc][k];
    float bias = dt_b[d0 + dloc];
#pragma unroll
    for (int lo = 0; lo < 32; lo++) {
      int l2 = lh * 32 + lo;
      float a0 = bias;
#pragma unroll
      for (int k = 0; k < 16; k++) a0 = fmaf(wreg[k], dtv[k][l2], a0);
      dout[dloc][l2] = fsoftplus(a0);
    }
    __syncthreads();
#pragma unroll
    for (int j = 0; j < 32; j++) {
      int idx = j * 256 + tid;
      int dd = idx & 127;
      int l2 = idx >> 7;
      dl_out[((size_t)b * LL + l0 + l2) * DN + d0 + dd] = dout[dd][l2];
    }
    __syncthreads();
  }
}

// ---------------------------------------------------------------------------
// Scan: lane = channel d, 16 states in registers. u/delta/z_t/y in [b][t][d]
// (all coalesced), B/C [b][t][n] wave-uniform float4. y in place over u.
// ---------------------------------------------------------------------------
#define HSTEP(n, Bcomp, Ccomp)                      \
  {                                                 \
    float e_ = __expf(dc * Av[n]);                  \
    h[n] = fmaf(e_, h[n], dlu * (Bcomp));           \
    if (PHASE == 3) acc = fmaf(h[n], (Ccomp), acc); \
  }

template <int PHASE>
__global__ __launch_bounds__(256) void scan_kernel(
    float* __restrict__ uy_f, float* __restrict__ uy_r,
    const float* __restrict__ dl_f, const float* __restrict__ dl_r,
    const float* __restrict__ z_t, const float* __restrict__ B_f,
    const float* __restrict__ C_f, const float* __restrict__ B_r,
    const float* __restrict__ C_r, const float* __restrict__ A_log,
    const float* __restrict__ Ab_log, const float* __restrict__ D_f,
    const float* __restrict__ D_r, float* __restrict__ hend,
    float* __restrict__ sumdl) {
  const int G2 = 2 * BB * DN;                            // 4096
  const int ch = (blockIdx.x & 15) * 256 + threadIdx.x;  // channel
  const int chunk = blockIdx.x >> 4;                     // 0..NC2-1
  const bool rev = ch >= BB * DN;                        // uniform per block
  const int cid = rev ? ch - BB * DN : ch;
  const int b = cid >> 9;
  const int d = cid & (DN - 1);

  const float* Arow = (rev ? Ab_log : A_log) + d * NS;
  float Av[NS];
#pragma unroll
  for (int n = 0; n < NS; n++) Av[n] = -__expf(Arow[n]);
  const float Dd = (rev ? D_r : D_f)[d];

  float* uy = (rev ? uy_r : uy_f) + (size_t)b * LL * DN + d;
  const float* dlp = (rev ? dl_r : dl_f) + (size_t)b * LL * DN + d;
  const float* Bp = (rev ? B_r : B_f) + (size_t)b * LL * NS;
  const float* Cp = (rev ? C_r : C_f) + (size_t)b * LL * NS;
  const float* zp = z_t + (size_t)b * LL * DN + d;

  float h[NS];
  if (PHASE == 3) {
    const float* hp = hend + ((size_t)chunk * G2 + ch) * NS;
#pragma unroll
    for (int n = 0; n < NS; n++) h[n] = hp[n];
  } else {
#pragma unroll
    for (int n = 0; n < NS; n++) h[n] = 0.f;
  }

  const int tstep = rev ? -1 : 1;
  int t = rev ? (LL - 1 - CL2 * chunk) : (CL2 * chunk);
  float sdl = 0.f;
  float uc = uy[(size_t)t * DN];
  float dc = dlp[(size_t)t * DN];
  float zc = (PHASE == 3) ? zp[(size_t)t * DN] : 0.f;

  for (int s = 0; s < CL2; s++) {
    int tn = t + tstep;
    int tcl = tn < 0 ? 0 : (tn >= LL ? LL - 1 : tn);
    float un = uy[(size_t)tcl * DN];
    float dn_ = dlp[(size_t)tcl * DN];
    float zn = (PHASE == 3) ? zp[(size_t)tcl * DN] : 0.f;

    const float4* B4 = (const float4*)(Bp + (size_t)t * NS);
    float4 Bq0 = B4[0], Bq1 = B4[1], Bq2 = B4[2], Bq3 = B4[3];
    float4 Cq0 = {0, 0, 0, 0}, Cq1 = {0, 0, 0, 0}, Cq2 = {0, 0, 0, 0},
           Cq3 = {0, 0, 0, 0};
    if (PHASE == 3) {
      const float4* C4 = (const float4*)(Cp + (size_t)t * NS);
      Cq0 = C4[0]; Cq1 = C4[1]; Cq2 = C4[2]; Cq3 = C4[3];
    }
    const float dlu = dc * uc;
    float acc = 0.f;
    HSTEP(0, Bq0.x, Cq0.x)  HSTEP(1, Bq0.y, Cq0.y)
    HSTEP(2, Bq0.z, Cq0.z)  HSTEP(3, Bq0.w, Cq0.w)
    HSTEP(4, Bq1.x, Cq1.x)  HSTEP(5, Bq1.y, Cq1.y)
    HSTEP(6, Bq1.z, Cq1.z)  HSTEP(7, Bq1.w, Cq1.w)
    HSTEP(8, Bq2.x, Cq2.x)  HSTEP(9, Bq2.y, Cq2.y)
    HSTEP(10, Bq2.z, Cq2.z) HSTEP(11, Bq2.w, Cq2.w)
    HSTEP(12, Bq3.x, Cq3.x) HSTEP(13, Bq3.y, Cq3.y)
    HSTEP(14, Bq3.z, Cq3.z) HSTEP(15, Bq3.w, Cq3.w)
    if (PHASE == 1) sdl += dc;
    if (PHASE == 3) {
      float y = fmaf(uc, Dd, acc) * zc;
      uy[(size_t)t * DN] = y;
    }
    t = tn; uc = un; dc = dn_; zc = zn;
  }
  if (PHASE == 1) {
    float* hp = hend + ((size_t)chunk * G2 + ch) * NS;
#pragma unroll
    for (int n = 0; n < NS; n++) hp[n] = h[n];
    sumdl[(size_t)chunk * G2 + ch] = sdl;
  }
}
#undef HSTEP

// Phase 2 (in-place): hend[c] <- h0[c] = H_{c-1}; H_c = exp(Av*sumdl[c])*H + hend[c]
__global__ __launch_bounds__(256) void scan_combine_kernel(
    const float* __restrict__ A_log, const float* __restrict__ Ab_log,
    float* __restrict__ hend, const float* __restrict__ sumdl) {
  const int G2 = 2 * BB * DN;
  const int gtid = blockIdx.x * 256 + threadIdx.x;
  const int ch = gtid >> 4;
  const int n = gtid & 15;
  const bool rev = ch >= BB * DN;
  const int d = ch & (DN - 1);
  const float Av = -__expf((rev ? Ab_log : A_log)[d * NS + n]);
  float H = 0.f;
  for (int c = 0; c < NC2; c++) {
    size_t idx = ((size_t)c * G2 + ch) * NS + n;
    float tmp = hend[idx];
    hend[idx] = H;
    if (c < NC2 - 1)
      H = fmaf(__expf(Av * sumdl[(size_t)c * G2 + ch]), H, tmp);
  }
}

// ---------------------------------------------------------------------------
// out_proj via bf16 MFMA: C[l][m] = sum_d 0.5*(yf+yr)[b][l][d] * ow[m][d].
// Block 64l x 64m, 4 waves (2x2), wave 32x32 = 2x2 MFMA tiles, K=512.
// ---------------------------------------------------------------------------
__global__ __launch_bounds__(256) void out_proj_mfma(
    const float* __restrict__ yf, const float* __restrict__ yr,
    const float* __restrict__ ow, float* __restrict__ outp) {
  __shared__ unsigned short yt[64][40];
  __shared__ unsigned short wo[64][40];
  const int b = blockIdx.z;
  const int m0 = blockIdx.y * 64;
  const int l0 = blockIdx.x * 64;
  const int tid = threadIdx.x;
  const int lane = tid & 63;
  const int wid = tid >> 6;
  const int wm = wid >> 1, wn = wid & 1;
  const int krow = (lane >> 4) * 8;
  const int rlo = lane & 15;

  f32x4 acc[2][2];
#pragma unroll
  for (int i = 0; i < 2; i++)
#pragma unroll
    for (int j = 0; j < 2; j++) acc[i][j] = (f32x4){0.f, 0.f, 0.f, 0.f};

  for (int dk = 0; dk < DN; dk += 32) {
    {
      int row = tid >> 2;
      int seg = (tid & 3) * 8;
      const float* ya = yf + ((size_t)b * LL + l0 + row) * DN + dk + seg;
      const float* yb = yr + ((size_t)b * LL + l0 + row) * DN + dk + seg;
      float4 a0 = *(const float4*)ya, a1 = *(const float4*)(ya + 4);
      float4 b0 = *(const float4*)yb, b1 = *(const float4*)(yb + 4);
      ushort8 yv;
      yv[0] = f2bf(0.5f * (a0.x + b0.x)); yv[1] = f2bf(0.5f * (a0.y + b0.y));
      yv[2] = f2bf(0.5f * (a0.z + b0.z)); yv[3] = f2bf(0.5f * (a0.w + b0.w));
      yv[4] = f2bf(0.5f * (a1.x + b1.x)); yv[5] = f2bf(0.5f * (a1.y + b1.y));
      yv[6] = f2bf(0.5f * (a1.z + b1.z)); yv[7] = f2bf(0.5f * (a1.w + b1.w));
      *(ushort8*)&yt[row][seg] = yv;
      const float* wp = ow + (size_t)(m0 + row) * DN + dk + seg;
      float4 w0 = *(const float4*)wp, w1 = *(const float4*)(wp + 4);
      ushort8 wv;
      wv[0] = f2bf(w0.x); wv[1] = f2bf(w0.y); wv[2] = f2bf(w0.z); wv[3] = f2bf(w0.w);
      wv[4] = f2bf(w1.x); wv[5] = f2bf(w1.y); wv[6] = f2bf(w1.z); wv[7] = f2bf(w1.w);
      *(ushort8*)&wo[row][seg] = wv;
    }
    __syncthreads();
    bf16x8 a0 = *(bf16x8*)&yt[wm * 32 + rlo][krow];
    bf16x8 a1 = *(bf16x8*)&yt[wm * 32 + 16 + rlo][krow];
    bf16x8 b0 = *(bf16x8*)&wo[wn * 32 + rlo][krow];
    bf16x8 b1 = *(bf16x8*)&wo[wn * 32 + 16 + rlo][krow];
    acc[0][0] = __builtin_amdgcn_mfma_f32_16x16x32_bf16(a0, b0, acc[0][0], 0, 0, 0);
    acc[0][1] = __builtin_amdgcn_mfma_f32_16x16x32_bf16(a0, b1, acc[0][1], 0, 0, 0);
    acc[1][0] = __builtin_amdgcn_mfma_f32_16x16x32_bf16(a1, b0, acc[1][0], 0, 0, 0);
    acc[1][1] = __builtin_amdgcn_mfma_f32_16x16x32_bf16(a1, b1, acc[1][1], 0, 0, 0);
    __syncthreads();
  }
#pragma unroll
  for (int mt = 0; mt < 2; mt++)
#pragma unroll
    for (int nt = 0; nt < 2; nt++)
#pragma unroll
      for (int r = 0; r < 4; r++) {
        int l = l0 + wm * 32 + mt * 16 + (lane >> 4) * 4 + r;
        int m = m0 + wn * 32 + nt * 16 + rlo;
        outp[((size_t)b * LL + l) * DM + m] = acc[mt][nt][r];
      }
}

// ---------------------------------------------------------------------------
extern "C" void kernel_launch(void* const* d_in, const int* in_sizes, int n_in,
                              void* d_out, int out_size, void* d_ws, size_t ws_size,
                              hipStream_t stream) {
  (void)in_sizes; (void)n_in; (void)out_size; (void)ws_size;
  const float* A_log = (const float*)d_in[2];
  const float* Ab_log = (const float*)d_in[3];

  float* ws = (float*)d_ws;
  float* xz = ws;                              // BB*DN*LL  (x rows only)
  float* z_t = xz + (size_t)BB * DN * LL;      // BB*LL*DN  silu(z) transposed
  float* u_f = z_t + (size_t)BB * LL * DN;     // BB*LL*DN  (u -> y in place)
  float* u_r = u_f + (size_t)BB * LL * DN;
  float* dl_f = u_r + (size_t)BB * LL * DN;
  float* dl_r = dl_f + (size_t)BB * LL * DN;
  float* B_f = dl_r + (size_t)BB * LL * DN;    // BB*LL*NS
  float* C_f = B_f + (size_t)BB * LL * NS;
  float* B_r = C_f + (size_t)BB * LL * NS;
  float* C_r = B_r + (size_t)BB * LL * NS;
  float* hend = C_r + (size_t)BB * LL * NS;    // NC2*G2*NS
  float* sumdl = hend + (size_t)NC2 * 2 * BB * DN * NS;  // NC2*G2

  for (int s = 0; s < 2; s++) {
    const int p = 4 + s * 14;
    const float* hin = (const float*)d_in[s];
    const float* in_w = (const float*)d_in[p + 0];
    const float* conv_w = (const float*)d_in[p + 1];
    const float* conv_b = (const float*)d_in[p + 2];
    const float* x_w = (const float*)d_in[p + 3];
    const float* dt_w = (const float*)d_in[p + 4];
    const float* dt_b = (const float*)d_in[p + 5];
    const float* Dp = (const float*)d_in[p + 6];
    const float* conv_w_b = (const float*)d_in[p + 7];
    const float* conv_b_b = (const float*)d_in[p + 8];
    const float* x_w_b = (const float*)d_in[p + 9];
    const float* dt_w_b = (const float*)d_in[p + 10];
    const float* dt_b_b = (const float*)d_in[p + 11];
    const float* Dp_b = (const float*)d_in[p + 12];
    const float* out_w = (const float*)d_in[p + 13];
    float* outp = (float*)d_out + (size_t)s * BB * LL * DM;

    hipLaunchKernelGGL(in_proj_mfma, dim3(LL / 128, EE / 128, BB), dim3(256), 0,
                       stream, hin, in_w, xz, z_t);
    hipLaunchKernelGGL(conv_kernel, dim3((LL / 32) * 4, BB, 2), dim3(256), 0,
                       stream, xz, conv_w, conv_b, conv_w_b, conv_b_b, u_f, u_r);
    hipLaunchKernelGGL(xdbl_kernel, dim3(LL / 64, BB, 2), dim3(256), 0, stream,
                       u_f, u_r, x_w, dt_w, dt_b, x_w_b, dt_w_b, dt_b_b,
                       dl_f, B_f, C_f, dl_r, B_r, C_r);
    hipLaunchKernelGGL(HIP_KERNEL_NAME(scan_kernel<1>), dim3(NC2 * 16), dim3(256), 0,
                       stream, u_f, u_r, dl_f, dl_r, z_t, B_f, C_f, B_r, C_r, A_log,
                       Ab_log, Dp, Dp_b, hend, sumdl);
    hipLaunchKernelGGL(scan_combine_kernel, dim3(2 * BB * DN * NS / 256), dim3(256),
                       0, stream, A_log, Ab_log, hend, sumdl);
    hipLaunchKernelGGL(HIP_KERNEL_NAME(scan_kernel<3>), dim3(NC2 * 16), dim3(256), 0,
                       stream, u_f, u_r, dl_f, dl_r, z_t, B_f, C_f, B_r, C_r, A_log,
                       Ab_log, Dp, Dp_b, hend, sumdl);
    hipLaunchKernelGGL(out_proj_mfma, dim3(LL / 64, DM / 64, BB), dim3(256), 0,
                       stream, u_f, u_r, out_w, outp);
  }
}

// Round 10
// 386.878 us; speedup vs baseline: 1.1412x; 1.1412x over previous
//
#include <hip/hip_runtime.h>
#include <hip/hip_bf16.h>
#include <cstddef>

#define BB 4
#define LL 2048
#define DM 256
#define DN 512
#define EE 1024
#define NS 16
#define RK 16
#define NC2 64          // scan chunks
#define CL2 (LL / NC2)  // chunk length = 32

typedef __attribute__((ext_vector_type(8))) short bf16x8;
typedef __attribute__((ext_vector_type(8))) unsigned short ushort8;
typedef __attribute__((ext_vector_type(4))) unsigned short ushort4v;
typedef __attribute__((ext_vector_type(4))) float f32x4;

__device__ __forceinline__ float fsilu(float x) { return x / (1.0f + __expf(-x)); }
__device__ __forceinline__ float fsoftplus(float x) { return x > 20.0f ? x : log1pf(__expf(x)); }
__device__ __forceinline__ unsigned short f2bf(float x) {  // RNE float->bf16
  union { float f; unsigned int u; } v; v.f = x;
  unsigned int r = v.u + 0x7fffu + ((v.u >> 16) & 1u);
  return (unsigned short)(r >> 16);
}

// ---------------------------------------------------------------------------
// in_proj via bf16 MFMA. Block: 128e x 128l, 4 waves (2x2), wave 64x64 =
// 4x4 MFMA 16x16x32. x-blocks (e<DN): C[e][l] -> xz[b][e][l].
// z-blocks: swap A/B so C[l][d] -> z_t[b][l][d] = silu (coalesced).
// ---------------------------------------------------------------------------
__global__ __launch_bounds__(256) void in_proj_mfma(
    const float* __restrict__ h, const float* __restrict__ w,
    float* __restrict__ xz, float* __restrict__ z_t) {
  __shared__ unsigned short ht[128][40];  // [l][k] bf16, 80B row (16B aligned)
  __shared__ unsigned short wt[128][40];  // [e][k]
  const int b = blockIdx.z;
  const int e0 = blockIdx.y * 128;
  const int l0 = blockIdx.x * 128;
  const int tid = threadIdx.x;
  const int lane = tid & 63;
  const int wid = tid >> 6;
  const int wm = wid >> 1, wn = wid & 1;
  const bool zblk = (e0 >= DN);
  const int krow = (lane >> 4) * 8;
  const int rlo = lane & 15;

  f32x4 acc[4][4];
#pragma unroll
  for (int i = 0; i < 4; i++)
#pragma unroll
    for (int j = 0; j < 4; j++) acc[i][j] = (f32x4){0.f, 0.f, 0.f, 0.f};

  for (int dk = 0; dk < DM; dk += 32) {
#pragma unroll
    for (int it = 0; it < 2; it++) {
      int idx = it * 256 + tid;
      int row = idx >> 2;
      int seg = (idx & 3) * 8;
      const float* hp = h + ((size_t)b * LL + l0 + row) * DM + dk + seg;
      float4 ha = *(const float4*)hp, hb = *(const float4*)(hp + 4);
      ushort8 hv;
      hv[0] = f2bf(ha.x); hv[1] = f2bf(ha.y); hv[2] = f2bf(ha.z); hv[3] = f2bf(ha.w);
      hv[4] = f2bf(hb.x); hv[5] = f2bf(hb.y); hv[6] = f2bf(hb.z); hv[7] = f2bf(hb.w);
      *(ushort8*)&ht[row][seg] = hv;
      const float* wp = w + (size_t)(e0 + row) * DM + dk + seg;
      float4 wa = *(const float4*)wp, wb = *(const float4*)(wp + 4);
      ushort8 wv;
      wv[0] = f2bf(wa.x); wv[1] = f2bf(wa.y); wv[2] = f2bf(wa.z); wv[3] = f2bf(wa.w);
      wv[4] = f2bf(wb.x); wv[5] = f2bf(wb.y); wv[6] = f2bf(wb.z); wv[7] = f2bf(wb.w);
      *(ushort8*)&wt[row][seg] = wv;
    }
    __syncthreads();
    unsigned short (*Ab)[40] = zblk ? ht : wt;
    unsigned short (*Bb)[40] = zblk ? wt : ht;
    bf16x8 af[4], bfr[4];
#pragma unroll
    for (int mt = 0; mt < 4; mt++)
      af[mt] = *(bf16x8*)&Ab[wm * 64 + mt * 16 + rlo][krow];
#pragma unroll
    for (int nt = 0; nt < 4; nt++)
      bfr[nt] = *(bf16x8*)&Bb[wn * 64 + nt * 16 + rlo][krow];
#pragma unroll
    for (int mt = 0; mt < 4; mt++)
#pragma unroll
      for (int nt = 0; nt < 4; nt++)
        acc[mt][nt] = __builtin_amdgcn_mfma_f32_16x16x32_bf16(
            af[mt], bfr[nt], acc[mt][nt], 0, 0, 0);
    __syncthreads();
  }
  if (!zblk) {
#pragma unroll
    for (int mt = 0; mt < 4; mt++)
#pragma unroll
      for (int nt = 0; nt < 4; nt++)
#pragma unroll
        for (int r = 0; r < 4; r++) {
          int e = e0 + wm * 64 + mt * 16 + (lane >> 4) * 4 + r;
          int l = l0 + wn * 64 + nt * 16 + rlo;
          xz[((size_t)b * DN + e) * LL + l] = acc[mt][nt][r];
        }
  } else {
#pragma unroll
    for (int mt = 0; mt < 4; mt++)
#pragma unroll
      for (int nt = 0; nt < 4; nt++)
#pragma unroll
        for (int r = 0; r < 4; r++) {
          int l = l0 + wm * 64 + mt * 16 + (lane >> 4) * 4 + r;
          int d = (e0 - DN) + wn * 64 + nt * 16 + rlo;
          z_t[((size_t)b * LL + l) * DN + d] = fsilu(acc[mt][nt][r]);
        }
  }
}

// ---------------------------------------------------------------------------
// conv_kernel: pure streaming conv+silu+transpose. Block = (128 d-chunk, 32 l).
// ---------------------------------------------------------------------------
__global__ __launch_bounds__(256) void conv_kernel(
    const float* __restrict__ xz,
    const float* __restrict__ cw_f, const float* __restrict__ cb_f,
    const float* __restrict__ cw_r, const float* __restrict__ cb_r,
    float* __restrict__ u_f, float* __restrict__ u_r) {
  __shared__ float xt[128][33];
  const int rev = blockIdx.z;
  const int b = blockIdx.y;
  const int dc0 = (blockIdx.x & 3) * 128;
  const int l0 = (blockIdx.x >> 2) * 32;
  const int tid = threadIdx.x;
  const int lc = tid & 31;
  const int dg = tid >> 5;  // 0..7
  const int l = l0 + lc;
  const float* conv_w = rev ? cw_r : cw_f;
  const float* conv_b = rev ? cb_r : cb_f;
  float* u_out = rev ? u_r : u_f;

#pragma unroll
  for (int i = 0; i < 16; i++) {
    int dloc = dg * 16 + i;
    int dd = dc0 + dloc;
    const float* base = xz + ((size_t)b * DN + dd) * LL;
    float4 cw4 = *(const float4*)(conv_w + dd * 4);
    float a0 = conv_b[dd];
    if (rev) {
      a0 = fmaf(cw4.w, base[l], a0);
      if (l + 1 < LL) a0 = fmaf(cw4.z, base[l + 1], a0);
      if (l + 2 < LL) a0 = fmaf(cw4.y, base[l + 2], a0);
      if (l + 3 < LL) a0 = fmaf(cw4.x, base[l + 3], a0);
    } else {
      a0 = fmaf(cw4.w, base[l], a0);
      if (l - 1 >= 0) a0 = fmaf(cw4.z, base[l - 1], a0);
      if (l - 2 >= 0) a0 = fmaf(cw4.y, base[l - 2], a0);
      if (l - 3 >= 0) a0 = fmaf(cw4.x, base[l - 3], a0);
    }
    xt[dloc][lc] = fsilu(a0);
  }
  __syncthreads();
#pragma unroll
  for (int j = 0; j < 16; j++) {
    int idx = j * 256 + tid;
    int dd = idx & 127;
    int l2 = idx >> 7;
    u_out[((size_t)b * LL + l0 + l2) * DN + dc0 + dd] = xt[dd][l2];
  }
}

// ---------------------------------------------------------------------------
// prep: convert x_w (48x512 fp32) of both branches to bf16 global.
// ---------------------------------------------------------------------------
__global__ __launch_bounds__(256) void xw_prep_kernel(
    const float* __restrict__ xw_f, const float* __restrict__ xw_r,
    unsigned short* __restrict__ o_f, unsigned short* __restrict__ o_r) {
  int i = blockIdx.x * 256 + threadIdx.x;
  if (i < 48 * 512) {
    o_f[i] = f2bf(xw_f[i]);
    o_r[i] = f2bf(xw_r[i]);
  }
}

// ---------------------------------------------------------------------------
// xdbl_kernel: x_dbl GEMM (48 x 16l x 512) + fused delta. Block = 16 l,
// 4 waves each owning a 128-k chunk (12 MFMA), partials reduced via LDS.
// A-fragments read directly from bf16 x_w in global (L2-resident, 48 KB).
// Grid (LL/16, BB, 2) = 1024 blocks.
// ---------------------------------------------------------------------------
__global__ __launch_bounds__(256) void xdbl_kernel(
    const float* __restrict__ u_f, const float* __restrict__ u_r,
    const unsigned short* __restrict__ xwb_f,
    const unsigned short* __restrict__ xwb_r,
    const float* __restrict__ dtw_f, const float* __restrict__ dtb_f,
    const float* __restrict__ dtw_r, const float* __restrict__ dtb_r,
    float* __restrict__ dl_f, float* __restrict__ B_f, float* __restrict__ C_f,
    float* __restrict__ dl_r, float* __restrict__ B_r, float* __restrict__ C_r) {
  __shared__ __align__(16) unsigned short ub[4][16][136];  // u tile bf16, per k-chunk
  __shared__ float red[4][48][17];                         // per-wave partials
  __shared__ float dtv[16][17];                            // dt rows
  const int rev = blockIdx.z;
  const int b = blockIdx.y;
  const int l0 = blockIdx.x * 16;
  const int tid = threadIdx.x;
  const int lane = tid & 63;
  const int w = tid >> 6;  // wave = k-chunk 0..3
  const int rlo = lane & 15;
  const int hi4 = lane >> 4;  // 0..3
  const int kseg = hi4 * 8;

  const float* up = (rev ? u_r : u_f) + ((size_t)b * LL + l0) * DN;
  const unsigned short* xwb = rev ? xwb_r : xwb_f;
  const float* dt_w = rev ? dtw_r : dtw_f;
  const float* dt_b = rev ? dtb_r : dtb_f;
  float* dl_out = rev ? dl_r : dl_f;
  float* B_out = rev ? B_r : B_f;
  float* C_out = rev ? C_r : C_f;

  // stage u tile [16 l][512 d] -> bf16 (chunked [4][16][136])
#pragma unroll
  for (int j = 0; j < 8; j++) {
    int idx = j * 256 + tid;  // 0..2047 float4 units
    int l2 = idx >> 7;        // 0..15
    int c4 = idx & 127;       // float4 col
    float4 v = *(const float4*)(up + (size_t)l2 * DN + c4 * 4);
    ushort4v t4;
    t4[0] = f2bf(v.x); t4[1] = f2bf(v.y); t4[2] = f2bf(v.z); t4[3] = f2bf(v.w);
    *(ushort4v*)&ub[c4 >> 5][l2][(c4 & 31) * 4] = t4;
  }
  __syncthreads();

  f32x4 am0 = (f32x4){0.f, 0.f, 0.f, 0.f};
  f32x4 am1 = (f32x4){0.f, 0.f, 0.f, 0.f};
  f32x4 am2 = (f32x4){0.f, 0.f, 0.f, 0.f};
#pragma unroll
  for (int ks = 0; ks < 4; ks++) {
    bf16x8 bfrag = *(bf16x8*)&ub[w][rlo][ks * 32 + kseg];
    const unsigned short* xp = xwb + (size_t)(w * 128 + ks * 32 + kseg);
    bf16x8 a0 = *(const bf16x8*)(xp + (size_t)(0 + rlo) * 512);
    bf16x8 a1 = *(const bf16x8*)(xp + (size_t)(16 + rlo) * 512);
    bf16x8 a2 = *(const bf16x8*)(xp + (size_t)(32 + rlo) * 512);
    am0 = __builtin_amdgcn_mfma_f32_16x16x32_bf16(a0, bfrag, am0, 0, 0, 0);
    am1 = __builtin_amdgcn_mfma_f32_16x16x32_bf16(a1, bfrag, am1, 0, 0, 0);
    am2 = __builtin_amdgcn_mfma_f32_16x16x32_bf16(a2, bfrag, am2, 0, 0, 0);
  }
  // write per-wave partials: out row = mt*16 + hi4*4 + r, col = rlo
  {
    const int rbase = hi4 * 4;
#pragma unroll
    for (int r = 0; r < 4; r++) red[w][0 + rbase + r][rlo] = am0[r];
#pragma unroll
    for (int r = 0; r < 4; r++) red[w][16 + rbase + r][rlo] = am1[r];
#pragma unroll
    for (int r = 0; r < 4; r++) red[w][32 + rbase + r][rlo] = am2[r];
  }
  __syncthreads();
  // reduce across waves + scatter
#pragma unroll
  for (int i = 0; i < 3; i++) {
    int o = i * 256 + tid;  // 0..767
    int row = o >> 4, col = o & 15;
    float s = (red[0][row][col] + red[1][row][col]) +
              (red[2][row][col] + red[3][row][col]);
    if (row < 16)
      dtv[row][col] = s;
    else if (row < 32)
      B_out[((size_t)b * LL + l0 + col) * NS + (row - 16)] = s;
    else
      C_out[((size_t)b * LL + l0 + col) * NS + (row - 32)] = s;
  }
  __syncthreads();
  // delta: thread handles d = tid and tid+256, all 16 l
#pragma unroll
  for (int half = 0; half < 2; half++) {
    int dd = half * 256 + tid;
    const float4* wr = (const float4*)(dt_w + (size_t)dd * RK);
    float4 w0 = wr[0], w1 = wr[1], w2 = wr[2], w3 = wr[3];
    float bias = dt_b[dd];
#pragma unroll
    for (int l2 = 0; l2 < 16; l2++) {
      float a0 = bias;
      a0 = fmaf(w0.x, dtv[0][l2], a0);  a0 = fmaf(w0.y, dtv[1][l2], a0);
      a0 = fmaf(w0.z, dtv[2][l2], a0);  a0 = fmaf(w0.w, dtv[3][l2], a0);
      a0 = fmaf(w1.x, dtv[4][l2], a0);  a0 = fmaf(w1.y, dtv[5][l2], a0);
      a0 = fmaf(w1.z, dtv[6][l2], a0);  a0 = fmaf(w1.w, dtv[7][l2], a0);
      a0 = fmaf(w2.x, dtv[8][l2], a0);  a0 = fmaf(w2.y, dtv[9][l2], a0);
      a0 = fmaf(w2.z, dtv[10][l2], a0); a0 = fmaf(w2.w, dtv[11][l2], a0);
      a0 = fmaf(w3.x, dtv[12][l2], a0); a0 = fmaf(w3.y, dtv[13][l2], a0);
      a0 = fmaf(w3.z, dtv[14][l2], a0); a0 = fmaf(w3.w, dtv[15][l2], a0);
      dl_out[((size_t)b * LL + l0 + l2) * DN + dd] = fsoftplus(a0);
    }
  }
}

// ---------------------------------------------------------------------------
// Scan: lane = channel d, 16 states in registers. u/delta/z_t/y in [b][t][d]
// (all coalesced), B/C [b][t][n] wave-uniform float4. y in place over u.
// ---------------------------------------------------------------------------
#define HSTEP(n, Bcomp, Ccomp)                      \
  {                                                 \
    float e_ = __expf(dc * Av[n]);                  \
    h[n] = fmaf(e_, h[n], dlu * (Bcomp));           \
    if (PHASE == 3) acc = fmaf(h[n], (Ccomp), acc); \
  }

template <int PHASE>
__global__ __launch_bounds__(256) void scan_kernel(
    float* __restrict__ uy_f, float* __restrict__ uy_r,
    const float* __restrict__ dl_f, const float* __restrict__ dl_r,
    const float* __restrict__ z_t, const float* __restrict__ B_f,
    const float* __restrict__ C_f, const float* __restrict__ B_r,
    const float* __restrict__ C_r, const float* __restrict__ A_log,
    const float* __restrict__ Ab_log, const float* __restrict__ D_f,
    const float* __restrict__ D_r, float* __restrict__ hend,
    float* __restrict__ sumdl) {
  const int G2 = 2 * BB * DN;                            // 4096
  const int ch = (blockIdx.x & 15) * 256 + threadIdx.x;  // channel
  const int chunk = blockIdx.x >> 4;                     // 0..NC2-1
  const bool rev = ch >= BB * DN;                        // uniform per block
  const int cid = rev ? ch - BB * DN : ch;
  const int b = cid >> 9;
  const int d = cid & (DN - 1);

  const float* Arow = (rev ? Ab_log : A_log) + d * NS;
  float Av[NS];
#pragma unroll
  for (int n = 0; n < NS; n++) Av[n] = -__expf(Arow[n]);
  const float Dd = (rev ? D_r : D_f)[d];

  float* uy = (rev ? uy_r : uy_f) + (size_t)b * LL * DN + d;
  const float* dlp = (rev ? dl_r : dl_f) + (size_t)b * LL * DN + d;
  const float* Bp = (rev ? B_r : B_f) + (size_t)b * LL * NS;
  const float* Cp = (rev ? C_r : C_f) + (size_t)b * LL * NS;
  const float* zp = z_t + (size_t)b * LL * DN + d;

  float h[NS];
  if (PHASE == 3) {
    const float* hp = hend + ((size_t)chunk * G2 + ch) * NS;
#pragma unroll
    for (int n = 0; n < NS; n++) h[n] = hp[n];
  } else {
#pragma unroll
    for (int n = 0; n < NS; n++) h[n] = 0.f;
  }

  const int tstep = rev ? -1 : 1;
  int t = rev ? (LL - 1 - CL2 * chunk) : (CL2 * chunk);
  float sdl = 0.f;
  float uc = uy[(size_t)t * DN];
  float dc = dlp[(size_t)t * DN];
  float zc = (PHASE == 3) ? zp[(size_t)t * DN] : 0.f;

  for (int s = 0; s < CL2; s++) {
    int tn = t + tstep;
    int tcl = tn < 0 ? 0 : (tn >= LL ? LL - 1 : tn);
    float un = uy[(size_t)tcl * DN];
    float dn_ = dlp[(size_t)tcl * DN];
    float zn = (PHASE == 3) ? zp[(size_t)tcl * DN] : 0.f;

    const float4* B4 = (const float4*)(Bp + (size_t)t * NS);
    float4 Bq0 = B4[0], Bq1 = B4[1], Bq2 = B4[2], Bq3 = B4[3];
    float4 Cq0 = {0, 0, 0, 0}, Cq1 = {0, 0, 0, 0}, Cq2 = {0, 0, 0, 0},
           Cq3 = {0, 0, 0, 0};
    if (PHASE == 3) {
      const float4* C4 = (const float4*)(Cp + (size_t)t * NS);
      Cq0 = C4[0]; Cq1 = C4[1]; Cq2 = C4[2]; Cq3 = C4[3];
    }
    const float dlu = dc * uc;
    float acc = 0.f;
    HSTEP(0, Bq0.x, Cq0.x)  HSTEP(1, Bq0.y, Cq0.y)
    HSTEP(2, Bq0.z, Cq0.z)  HSTEP(3, Bq0.w, Cq0.w)
    HSTEP(4, Bq1.x, Cq1.x)  HSTEP(5, Bq1.y, Cq1.y)
    HSTEP(6, Bq1.z, Cq1.z)  HSTEP(7, Bq1.w, Cq1.w)
    HSTEP(8, Bq2.x, Cq2.x)  HSTEP(9, Bq2.y, Cq2.y)
    HSTEP(10, Bq2.z, Cq2.z) HSTEP(11, Bq2.w, Cq2.w)
    HSTEP(12, Bq3.x, Cq3.x) HSTEP(13, Bq3.y, Cq3.y)
    HSTEP(14, Bq3.z, Cq3.z) HSTEP(15, Bq3.w, Cq3.w)
    if (PHASE == 1) sdl += dc;
    if (PHASE == 3) {
      float y = fmaf(uc, Dd, acc) * zc;
      uy[(size_t)t * DN] = y;
    }
    t = tn; uc = un; dc = dn_; zc = zn;
  }
  if (PHASE == 1) {
    float* hp = hend + ((size_t)chunk * G2 + ch) * NS;
#pragma unroll
    for (int n = 0; n < NS; n++) hp[n] = h[n];
    sumdl[(size_t)chunk * G2 + ch] = sdl;
  }
}
#undef HSTEP

// Phase 2 (in-place): hend[c] <- h0[c] = H_{c-1}; H_c = exp(Av*sumdl[c])*H + hend[c]
__global__ __launch_bounds__(256) void scan_combine_kernel(
    const float* __restrict__ A_log, const float* __restrict__ Ab_log,
    float* __restrict__ hend, const float* __restrict__ sumdl) {
  const int G2 = 2 * BB * DN;
  const int gtid = blockIdx.x * 256 + threadIdx.x;
  const int ch = gtid >> 4;
  const int n = gtid & 15;
  const bool rev = ch >= BB * DN;
  const int d = ch & (DN - 1);
  const float Av = -__expf((rev ? Ab_log : A_log)[d * NS + n]);
  float H = 0.f;
  for (int c = 0; c < NC2; c++) {
    size_t idx = ((size_t)c * G2 + ch) * NS + n;
    float tmp = hend[idx];
    hend[idx] = H;
    if (c < NC2 - 1)
      H = fmaf(__expf(Av * sumdl[(size_t)c * G2 + ch]), H, tmp);
  }
}

// ---------------------------------------------------------------------------
// out_proj via bf16 MFMA: C[l][m] = sum_d 0.5*(yf+yr)[b][l][d] * ow[m][d].
// Block 64l x 64m, 4 waves (2x2), wave 32x32 = 2x2 MFMA tiles, K=512.
// ---------------------------------------------------------------------------
__global__ __launch_bounds__(256) void out_proj_mfma(
    const float* __restrict__ yf, const float* __restrict__ yr,
    const float* __restrict__ ow, float* __restrict__ outp) {
  __shared__ unsigned short yt[64][40];
  __shared__ unsigned short wo[64][40];
  const int b = blockIdx.z;
  const int m0 = blockIdx.y * 64;
  const int l0 = blockIdx.x * 64;
  const int tid = threadIdx.x;
  const int lane = tid & 63;
  const int wid = tid >> 6;
  const int wm = wid >> 1, wn = wid & 1;
  const int krow = (lane >> 4) * 8;
  const int rlo = lane & 15;

  f32x4 acc[2][2];
#pragma unroll
  for (int i = 0; i < 2; i++)
#pragma unroll
    for (int j = 0; j < 2; j++) acc[i][j] = (f32x4){0.f, 0.f, 0.f, 0.f};

  for (int dk = 0; dk < DN; dk += 32) {
    {
      int row = tid >> 2;
      int seg = (tid & 3) * 8;
      const float* ya = yf + ((size_t)b * LL + l0 + row) * DN + dk + seg;
      const float* yb = yr + ((size_t)b * LL + l0 + row) * DN + dk + seg;
      float4 a0 = *(const float4*)ya, a1 = *(const float4*)(ya + 4);
      float4 b0 = *(const float4*)yb, b1 = *(const float4*)(yb + 4);
      ushort8 yv;
      yv[0] = f2bf(0.5f * (a0.x + b0.x)); yv[1] = f2bf(0.5f * (a0.y + b0.y));
      yv[2] = f2bf(0.5f * (a0.z + b0.z)); yv[3] = f2bf(0.5f * (a0.w + b0.w));
      yv[4] = f2bf(0.5f * (a1.x + b1.x)); yv[5] = f2bf(0.5f * (a1.y + b1.y));
      yv[6] = f2bf(0.5f * (a1.z + b1.z)); yv[7] = f2bf(0.5f * (a1.w + b1.w));
      *(ushort8*)&yt[row][seg] = yv;
      const float* wp = ow + (size_t)(m0 + row) * DN + dk + seg;
      float4 w0 = *(const float4*)wp, w1 = *(const float4*)(wp + 4);
      ushort8 wv;
      wv[0] = f2bf(w0.x); wv[1] = f2bf(w0.y); wv[2] = f2bf(w0.z); wv[3] = f2bf(w0.w);
      wv[4] = f2bf(w1.x); wv[5] = f2bf(w1.y); wv[6] = f2bf(w1.z); wv[7] = f2bf(w1.w);
      *(ushort8*)&wo[row][seg] = wv;
    }
    __syncthreads();
    bf16x8 a0 = *(bf16x8*)&yt[wm * 32 + rlo][krow];
    bf16x8 a1 = *(bf16x8*)&yt[wm * 32 + 16 + rlo][krow];
    bf16x8 b0 = *(bf16x8*)&wo[wn * 32 + rlo][krow];
    bf16x8 b1 = *(bf16x8*)&wo[wn * 32 + 16 + rlo][krow];
    acc[0][0] = __builtin_amdgcn_mfma_f32_16x16x32_bf16(a0, b0, acc[0][0], 0, 0, 0);
    acc[0][1] = __builtin_amdgcn_mfma_f32_16x16x32_bf16(a0, b1, acc[0][1], 0, 0, 0);
    acc[1][0] = __builtin_amdgcn_mfma_f32_16x16x32_bf16(a1, b0, acc[1][0], 0, 0, 0);
    acc[1][1] = __builtin_amdgcn_mfma_f32_16x16x32_bf16(a1, b1, acc[1][1], 0, 0, 0);
    __syncthreads();
  }
#pragma unroll
  for (int mt = 0; mt < 2; mt++)
#pragma unroll
    for (int nt = 0; nt < 2; nt++)
#pragma unroll
      for (int r = 0; r < 4; r++) {
        int l = l0 + wm * 32 + mt * 16 + (lane >> 4) * 4 + r;
        int m = m0 + wn * 32 + nt * 16 + rlo;
        outp[((size_t)b * LL + l) * DM + m] = acc[mt][nt][r];
      }
}

// ---------------------------------------------------------------------------
extern "C" void kernel_launch(void* const* d_in, const int* in_sizes, int n_in,
                              void* d_out, int out_size, void* d_ws, size_t ws_size,
                              hipStream_t stream) {
  (void)in_sizes; (void)n_in; (void)out_size; (void)ws_size;
  const float* A_log = (const float*)d_in[2];
  const float* Ab_log = (const float*)d_in[3];

  float* ws = (float*)d_ws;
  float* xz = ws;                              // BB*DN*LL  (x rows only)
  float* z_t = xz + (size_t)BB * DN * LL;      // BB*LL*DN  silu(z) transposed
  float* u_f = z_t + (size_t)BB * LL * DN;     // BB*LL*DN  (u -> y in place)
  float* u_r = u_f + (size_t)BB * LL * DN;
  float* dl_f = u_r + (size_t)BB * LL * DN;
  float* dl_r = dl_f + (size_t)BB * LL * DN;
  float* B_f = dl_r + (size_t)BB * LL * DN;    // BB*LL*NS
  float* C_f = B_f + (size_t)BB * LL * NS;
  float* B_r = C_f + (size_t)BB * LL * NS;
  float* C_r = B_r + (size_t)BB * LL * NS;
  float* hend = C_r + (size_t)BB * LL * NS;    // NC2*G2*NS
  float* sumdl = hend + (size_t)NC2 * 2 * BB * DN * NS;  // NC2*G2
  unsigned short* xwbf_f = (unsigned short*)(sumdl + (size_t)NC2 * 2 * BB * DN);
  unsigned short* xwbf_r = xwbf_f + 48 * 512;

  for (int s = 0; s < 2; s++) {
    const int p = 4 + s * 14;
    const float* hin = (const float*)d_in[s];
    const float* in_w = (const float*)d_in[p + 0];
    const float* conv_w = (const float*)d_in[p + 1];
    const float* conv_b = (const float*)d_in[p + 2];
    const float* x_w = (const float*)d_in[p + 3];
    const float* dt_w = (const float*)d_in[p + 4];
    const float* dt_b = (const float*)d_in[p + 5];
    const float* Dp = (const float*)d_in[p + 6];
    const float* conv_w_b = (const float*)d_in[p + 7];
    const float* conv_b_b = (const float*)d_in[p + 8];
    const float* x_w_b = (const float*)d_in[p + 9];
    const float* dt_w_b = (const float*)d_in[p + 10];
    const float* dt_b_b = (const float*)d_in[p + 11];
    const float* Dp_b = (const float*)d_in[p + 12];
    const float* out_w = (const float*)d_in[p + 13];
    float* outp = (float*)d_out + (size_t)s * BB * LL * DM;

    hipLaunchKernelGGL(in_proj_mfma, dim3(LL / 128, EE / 128, BB), dim3(256), 0,
                       stream, hin, in_w, xz, z_t);
    hipLaunchKernelGGL(xw_prep_kernel, dim3(96), dim3(256), 0, stream,
                       x_w, x_w_b, xwbf_f, xwbf_r);
    hipLaunchKernelGGL(conv_kernel, dim3((LL / 32) * 4, BB, 2), dim3(256), 0,
                       stream, xz, conv_w, conv_b, conv_w_b, conv_b_b, u_f, u_r);
    hipLaunchKernelGGL(xdbl_kernel, dim3(LL / 16, BB, 2), dim3(256), 0, stream,
                       u_f, u_r, xwbf_f, xwbf_r, dt_w, dt_b, dt_w_b, dt_b_b,
                       dl_f, B_f, C_f, dl_r, B_r, C_r);
    hipLaunchKernelGGL(HIP_KERNEL_NAME(scan_kernel<1>), dim3(NC2 * 16), dim3(256), 0,
                       stream, u_f, u_r, dl_f, dl_r, z_t, B_f, C_f, B_r, C_r, A_log,
                       Ab_log, Dp, Dp_b, hend, sumdl);
    hipLaunchKernelGGL(scan_combine_kernel, dim3(2 * BB * DN * NS / 256), dim3(256),
                       0, stream, A_log, Ab_log, hend, sumdl);
    hipLaunchKernelGGL(HIP_KERNEL_NAME(scan_kernel<3>), dim3(NC2 * 16), dim3(256), 0,
                       stream, u_f, u_r, dl_f, dl_r, z_t, B_f, C_f, B_r, C_r, A_log,
                       Ab_log, Dp, Dp_b, hend, sumdl);
    hipLaunchKernelGGL(out_proj_mfma, dim3(LL / 64, DM / 64, BB), dim3(256), 0,
                       stream, u_f, u_r, out_w, outp);
  }
}